// Round 26
// baseline (115.401 us; speedup 1.0000x reference)
//
#include <hip/hip_runtime.h>
#include <hip/hip_bf16.h>
#include <stdint.h>
#include <math.h>

#define SEQ   1024
#define NHEAD 12
#define HD    64
#define CDIM  768
#define MTOK  8192
#define NQKV  2304
#define NPAIR 96   // BS*NHEAD

// q pre-scale: 1/sqrt(64) * log2(e)  (softmax done base-2)
#define QSCALE 0.18033688011112042f

typedef uint16_t u16;
typedef __attribute__((ext_vector_type(8)))  __bf16 bf16x8;
typedef __attribute__((ext_vector_type(4)))  float  f32x4;
typedef __attribute__((ext_vector_type(16))) float  f32x16;

__device__ __forceinline__ u16 f32_to_bf16(float f) {
  union { float f; uint32_t u; } cv; cv.f = f;
  uint32_t u = cv.u;
  return (u16)((u + 0x7FFFu + ((u >> 16) & 1u)) >> 16);
}

__device__ __forceinline__ uint32_t cvt_pk_bf16(float lo, float hi) {
  uint32_t r;
  asm("v_cvt_pk_bf16_f32 %0, %1, %2" : "=v"(r) : "v"(lo), "v"(hi));
  return r;
}

// v_permlane32_swap_b32: a.hi <-> b.lo
__device__ __forceinline__ void pl32_swap(uint32_t& a, uint32_t& b) {
  asm("v_permlane32_swap_b32 %0, %1" : "+v"(a), "+v"(b));
}

__device__ __forceinline__ float vexp2(float x) {
  float r; asm("v_exp_f32 %0, %1" : "=v"(r) : "v"(x)); return r;
}
__device__ __forceinline__ float vmax3(float a, float b, float c) {
  float d; asm("v_max3_f32 %0, %1, %2, %3" : "=v"(d) : "v"(a), "v"(b), "v"(c)); return d;
}
__device__ __forceinline__ float vrcp(float x) {
  float r; asm("v_rcp_f32 %0, %1" : "=v"(r) : "v"(x)); return r;
}

__device__ __forceinline__ void load_lds16(const u16* g, u16* l) {
  __builtin_amdgcn_global_load_lds(
      (const __attribute__((address_space(1))) uint32_t*)g,
      (__attribute__((address_space(3))) uint32_t*)l, 16, 0, 0);
}

// swizzled LDS read: 16B at (row, col-byte cb) of a 128B-row tile
__device__ __forceinline__ bf16x8 ldsw(const u16* base, int r, int cb) {
  int byte = (r << 7) + cb;
  byte ^= ((r & 7) << 4);
  return *(const bf16x8*)((const char*)base + byte);
}

// swizzled LDS read for 64B-row tiles (BK=32): cb ^= ((r>>1)&3)<<4
__device__ __forceinline__ bf16x8 ldsw32(const u16* base, int r, int cb) {
  int byte = (r << 6) + (cb ^ (((r >> 1) & 3) << 4));
  return *(const bf16x8*)((const char*)base + byte);
}

// stage NB bytes (rows of 128B) from contiguous global, swizzled
template<int NB>
__device__ __forceinline__ void stage_swz(const u16* __restrict__ g, u16* l, int tid) {
  #pragma unroll
  for (int i = 0; i < NB / 4096; ++i) {
    int F = i * 4096 + tid * 16;
    int S = F ^ (((F >> 7) & 7) << 4);
    load_lds16(g + (S >> 1), l + (F >> 1));
  }
}

// stage V^T chunk: global vt[pair][d=64][n=1024], cols kc*64..+63 -> 64x128B tile
__device__ __forceinline__ void stage_vt(const u16* __restrict__ vtb, u16* l, int kc, int tid) {
  #pragma unroll
  for (int i = 0; i < 2; ++i) {
    int F = i * 4096 + tid * 16;
    int S = F ^ (((F >> 7) & 7) << 4);
    int r = S >> 7;
    int cb = S & 127;
    load_lds16(vtb + ((size_t)r << 10) + (kc << 6) + (cb >> 1), l + (F >> 1));
  }
}

// ---- fused prep: cvt_x (blocks 0..3071) | transpose w_qkv (3072..3503) |
// transpose w_o (3504..3647). ----
#define CVT_BLOCKS 3072                       // (MTOK*CDIM)/(256*8)
#define TQKV_BLOCKS 432                       // (CDIM/64)*(NQKV/64)
__global__ __launch_bounds__(256) void prep_kernel(const float* __restrict__ x,
                                                   u16* __restrict__ xb,
                                                   const float* __restrict__ wqkv,
                                                   u16* __restrict__ wqkvT,
                                                   const float* __restrict__ wo,
                                                   u16* __restrict__ woT) {
  __shared__ u16 t[64][66];
  int bid = blockIdx.x;
  int tid = threadIdx.x;

  if (bid < CVT_BLOCKS) {
    int i = bid * 256 + tid;
    const float4* p = (const float4*)x + (size_t)i * 2;
    float4 a = p[0], b = p[1];
    uint4 o;
    o.x = cvt_pk_bf16(a.x, a.y);
    o.y = cvt_pk_bf16(a.z, a.w);
    o.z = cvt_pk_bf16(b.x, b.y);
    o.w = cvt_pk_bf16(b.z, b.w);
    ((uint4*)xb)[i] = o;
    return;
  }

  const float* in;
  u16* outp;
  int N, bid2;
  if (bid < CVT_BLOCKS + TQKV_BLOCKS) {
    bid2 = bid - CVT_BLOCKS; in = wqkv; outp = wqkvT; N = NQKV;
  } else {
    bid2 = bid - CVT_BLOCKS - TQKV_BLOCKS; in = wo; outp = woT; N = CDIM;
  }
  const int K = CDIM, nbk = CDIM >> 6;        // 12
  int bk = bid2 % nbk, bn = bid2 / nbk;
  int k0 = bk << 6, n0 = bn << 6;
  #pragma unroll
  for (int i = 0; i < 16; ++i) {
    int idx = i * 256 + tid;
    int kr = idx >> 6, nc = idx & 63;
    t[kr][nc] = f32_to_bf16(in[(size_t)(k0 + kr) * N + n0 + nc]);
  }
  __syncthreads();
  #pragma unroll
  for (int i = 0; i < 16; ++i) {
    int idx = i * 256 + tid;
    int nr = idx >> 6, kc = idx & 63;
    outp[(size_t)(n0 + nr) * K + k0 + kc] = t[kc][nr];
  }
}

// ---- QKV GEMM v2: 128x128 tile, BK=32, 8 waves (512 thr, 4Mx2N, 32x64/wave),
// dbuf 32KB -> 4 blocks/CU = 32 waves/CU (HW cap); counted vmcnt(2);
// 64B-row swizzle; tn-major XCD order; r24 epilogue (4KB/wave repack). ----
__global__ __launch_bounds__(512) void gemm_qkv8(const u16* __restrict__ A,
                                                 const u16* __restrict__ Bt,
                                                 u16* __restrict__ qb,
                                                 u16* __restrict__ kb,
                                                 u16* __restrict__ vb) {
  __shared__ u16 SH[4][4096];   // [0,1]=A dbuf (8KB each), [2,3]=B dbuf; 32KB

  const int K = CDIM;
  int bid = blockIdx.x;
  int xcd = bid & 7, ii = bid >> 3;
  int tn = ii >> 3;
  int tm = (xcd << 3) + (ii & 7);
  int mBase = tm << 7, nBase = tn << 7;
  int tid = threadIdx.x;
  int lane = tid & 63, wid = tid >> 6;       // 0..7
  int wm = wid >> 1, wn = wid & 1;           // 4M x 2N
  int wr = wm << 5, wc = wn << 6;            // 32-row, 64-col wave tile
  int lr = lane & 15, lk = lane >> 4;

  const int nk = K >> 5;                     // 24

  auto STAGE = [&](int kt, int b) {
    int F = tid * 16;                        // 0..8191 (8KB tile)
    int row = F >> 6;                        // 0..127 (64B rows)
    int cb  = (F & 63) ^ (((row >> 1) & 3) << 4);
    load_lds16(A  + (size_t)(mBase + row) * K + kt * 32 + (cb >> 1), &SH[b][F >> 1]);
    load_lds16(Bt + (size_t)(nBase + row) * K + kt * 32 + (cb >> 1), &SH[2 + b][F >> 1]);
  };

  f32x4 acc[2][4] = {};

  STAGE(0, 0);
  for (int kt = 0; kt < nk; ++kt) {
    const int cur = kt & 1;
    if (kt + 1 < nk) {
      STAGE(kt + 1, cur ^ 1);
      asm volatile("s_waitcnt vmcnt(2)" ::: "memory");   // tile kt landed
    } else {
      asm volatile("s_waitcnt vmcnt(0)" ::: "memory");
    }
    __builtin_amdgcn_s_barrier();
    asm volatile("" ::: "memory");

    bf16x8 af[2], bfr[4];
    #pragma unroll
    for (int i2 = 0; i2 < 2; ++i2)
      af[i2]  = ldsw32(SH[cur], wr + i2 * 16 + lr, lk * 16);
    #pragma unroll
    for (int i2 = 0; i2 < 4; ++i2)
      bfr[i2] = ldsw32(SH[2 + cur], wc + i2 * 16 + lr, lk * 16);
    #pragma unroll
    for (int mi = 0; mi < 2; ++mi)
      #pragma unroll
      for (int ni = 0; ni < 4; ++ni)
        acc[mi][ni] = __builtin_amdgcn_mfma_f32_16x16x32_bf16(af[mi], bfr[ni], acc[mi][ni], 0, 0, 0);

    __builtin_amdgcn_s_barrier();
    asm volatile("" ::: "memory");
  }
  // trailing barrier above: all reads done; SH free for epilogue

  int c0 = nBase + wc;                 // 64-aligned; wave spans one head
  int s  = c0 / CDIM;
  int rem0 = c0 - s * CDIM, hh = rem0 >> 6;
  u16* ereg = &SH[0][0] + wid * 2048;  // 4KB per wave (8 waves = 32KB)

  if (s != 2) {
    // region 32 rows x 64 cols, 128B rows, XOR-swizzled
    #pragma unroll
    for (int mi = 0; mi < 2; ++mi)
      #pragma unroll
      for (int ni = 0; ni < 4; ++ni)
        #pragma unroll
        for (int j = 0; j < 4; ++j) {
          float val = acc[mi][ni][j];
          if (s == 0) val *= QSCALE;
          int r = mi * 16 + lk * 4 + j;      // 0..31
          int c = ni * 16 + lr;              // 0..63
          int byte = (r << 7) + (((c << 1)) ^ ((r & 7) << 4));
          *(u16*)((char*)ereg + byte) = f32_to_bf16(val);
        }
    int row = lane & 31, hf = lane >> 5;
    int mrow = mBase + wr + row;
    int bb = mrow >> 10, nn = mrow & 1023;
    u16* buf = (s == 0) ? qb : kb;
    u16* dst = buf + (((size_t)(bb * NHEAD + hh)) << 16) + nn * 64 + hf * 32;
    #pragma unroll
    for (int rc2 = 0; rc2 < 4; ++rc2) {
      int rc = (rc2 + (row >> 3)) & 3;
      int cbyte = hf * 64 + rc * 16;
      int byte = (row << 7) + (cbyte ^ ((row & 7) << 4));
      bf16x8 vv = *(const bf16x8*)((const char*)ereg + byte);
      *(bf16x8*)(dst + rc * 8) = vv;
    }
  } else {
    // vT slice: transpose to region 64 d-rows x 32 n-cols, 64B rows
    #pragma unroll
    for (int mi = 0; mi < 2; ++mi)
      #pragma unroll
      for (int ni = 0; ni < 4; ++ni)
        #pragma unroll
        for (int j = 0; j < 4; ++j) {
          int n_ = mi * 16 + lk * 4 + j;     // 0..31 (m-local)
          int d_ = ni * 16 + lr;             // 0..63
          int byte = (d_ << 6) + (((n_ << 1)) ^ (((d_ >> 1) & 3) << 4));
          *(u16*)((char*)ereg + byte) = f32_to_bf16(acc[mi][ni][j]);
        }
    int m0 = mBase + wr;
    int bb = m0 >> 10, nn0 = m0 & 1023;
    u16* dst = vb + (((size_t)(bb * NHEAD + hh)) << 16) + ((size_t)lane << 10) + nn0;
    #pragma unroll
    for (int rc2 = 0; rc2 < 4; ++rc2) {
      int rc = (rc2 + (lane >> 4)) & 3;
      int byte = (lane << 6) + ((rc * 16) ^ (((lane >> 1) & 3) << 4));
      bf16x8 vv = *(const bf16x8*)((const char*)ereg + byte);
      *(bf16x8*)(dst + rc * 8) = vv;
    }
  }
}

// ---- w_o GEMM (r25 proven): 8 waves, BK=64, dbuf + vmcnt(4), f32 repack ----
__global__ __launch_bounds__(512) void gemm_wo8(const u16* __restrict__ A,
                                                const u16* __restrict__ Bt,
                                                float* __restrict__ Cf) {
  __shared__ u16 SH[4][8192];

  const int K = CDIM, N = CDIM;
  int bid = blockIdx.x;
  int xcd = bid & 7, ii = bid >> 3;
  int tn = ii >> 3;
  int tm = (xcd << 3) + (ii & 7);
  int mBase = tm << 7, nBase = tn << 7;
  int tid = threadIdx.x;
  int lane = tid & 63, wid = tid >> 6;
  int wm = wid >> 1, wn = wid & 1;
  int wr = wm << 5, wc = wn << 6;
  int lr = lane & 15, lk = lane >> 4;

  const int nk = K >> 6;

  auto STAGE = [&](int kt, int b) {
    #pragma unroll
    for (int i2 = 0; i2 < 2; ++i2) {
      int F = i2 * 8192 + tid * 16;
      int row = F >> 7;
      int cb  = (F & 127) ^ ((row & 7) << 4);
      load_lds16(A + (size_t)(mBase + row) * K + kt * 64 + (cb >> 1), &SH[b][F >> 1]);
    }
    #pragma unroll
    for (int i2 = 0; i2 < 2; ++i2) {
      int F = i2 * 8192 + tid * 16;
      int row = F >> 7;
      int cb  = (F & 127) ^ ((row & 7) << 4);
      load_lds16(Bt + (size_t)(nBase + row) * K + kt * 64 + (cb >> 1), &SH[2 + b][F >> 1]);
    }
  };

  f32x4 acc[2][4] = {};

  STAGE(0, 0);
  for (int kt = 0; kt < nk; ++kt) {
    const int cur = kt & 1;
    if (kt + 1 < nk) {
      STAGE(kt + 1, cur ^ 1);
      asm volatile("s_waitcnt vmcnt(4)" ::: "memory");
    } else {
      asm volatile("s_waitcnt vmcnt(0)" ::: "memory");
    }
    __builtin_amdgcn_s_barrier();
    asm volatile("" ::: "memory");

    #pragma unroll
    for (int kk = 0; kk < 2; ++kk) {
      bf16x8 af[2], bfr[4];
      #pragma unroll
      for (int i2 = 0; i2 < 2; ++i2)
        af[i2]  = ldsw(SH[cur], wr + i2 * 16 + lr, kk * 64 + lk * 16);
      #pragma unroll
      for (int i2 = 0; i2 < 4; ++i2)
        bfr[i2] = ldsw(SH[2 + cur], wc + i2 * 16 + lr, kk * 64 + lk * 16);
      #pragma unroll
      for (int mi = 0; mi < 2; ++mi)
        #pragma unroll
        for (int ni = 0; ni < 4; ++ni)
          acc[mi][ni] = __builtin_amdgcn_mfma_f32_16x16x32_bf16(af[mi], bfr[ni], acc[mi][ni], 0, 0, 0);
    }

    __builtin_amdgcn_s_barrier();
    asm volatile("" ::: "memory");
  }

  // f32 repack: 32 rows x 256B, XOR-swizzled; 8KB/wave
  char* ereg = (char*)(&SH[0][0]) + wid * 8192;
  #pragma unroll
  for (int mi = 0; mi < 2; ++mi)
    #pragma unroll
    for (int ni = 0; ni < 4; ++ni)
      #pragma unroll
      for (int j = 0; j < 4; ++j) {
        int r = mi * 16 + lk * 4 + j;        // 0..31
        int byte = (r << 8) + (((ni * 16 + lr) << 2) ^ ((r & 7) << 4));
        *(float*)(ereg + byte) = acc[mi][ni][j];
      }
  int row = lane & 31, hf = lane >> 5;
  float* dst = Cf + (size_t)(mBase + wr + row) * N + (nBase + wc) + hf * 32;
  #pragma unroll
  for (int rc2 = 0; rc2 < 8; ++rc2) {
    int rc = (rc2 + (row >> 2)) & 7;
    int cbyte = hf * 128 + rc * 16;
    int byte = (row << 8) + (cbyte ^ ((row & 7) << 4));
    f32x4 vv = *(const f32x4*)(ereg + byte);
    *(f32x4*)(dst + rc * 4) = vv;
  }
}

// ---- flash attention v9 (r18 best): T15 pipeline, in-lane l ----
__global__ __launch_bounds__(256, 3) void attn_kernel(const u16* __restrict__ q,
                                                      const u16* __restrict__ k,
                                                      const u16* __restrict__ v,
                                                      u16* __restrict__ out) {
  __shared__ u16 Ks[2][4096];
  __shared__ u16 Vs[3][4096];   // V^T slots: chunk c -> slot c%3

  int bid = blockIdx.x;
  int wgid = (bid & 7) * 96 + (bid >> 3);   // 768 blocks, pairs XCD-local
  int pair = wgid >> 3;
  int qt   = wgid & 7;
  int b = pair / NHEAD, hh = pair - b * NHEAD;
  const u16* Kg  = k + ((size_t)pair << 16);
  const u16* Vtb = v + ((size_t)pair << 16);
  int tid = threadIdx.x, lane = tid & 63, wid = tid >> 6;
  int ql = lane & 31, hi = lane >> 5;

  const u16* Qrow = q + ((size_t)pair << 16) + (size_t)((qt << 7) + (wid << 5) + ql) * 64;
  bf16x8 qf[4];
  #pragma unroll
  for (int t = 0; t < 4; ++t)
    qf[t] = *(const bf16x8*)(Qrow + t * 16 + hi * 8);

  float m_ = -1e30f, l_ = 0.f;  // per-lane: q = ql, k-half = hi (l_ partial)
  f32x16 acc0 = {}, acc1 = {};
  f32x16 pA0, pA1, pB0, pB1;    // S-state: even chunks in pA, odd in pB

  auto SMPV = [&](f32x16& s0, f32x16& s1, const u16* vbase) {
    float a0 = vmax3(s0[0],  s0[1],  s0[2]);
    float a1 = vmax3(s0[3],  s0[4],  s0[5]);
    float a2 = vmax3(s0[6],  s0[7],  s0[8]);
    float a3 = vmax3(s0[9],  s0[10], s0[11]);
    float a4 = vmax3(s0[12], s0[13], s0[14]);
    float a5 = vmax3(s0[15], s1[0],  s1[1]);
    float a6 = vmax3(s1[2],  s1[3],  s1[4]);
    float a7 = vmax3(s1[5],  s1[6],  s1[7]);
    float a8 = vmax3(s1[8],  s1[9],  s1[10]);
    float a9 = vmax3(s1[11], s1[12], s1[13]);
    float aA = fmaxf(s1[14], s1[15]);
    float b0 = vmax3(a0, a1, a2);
    float b1 = vmax3(a3, a4, a5);
    float b2 = vmax3(a6, a7, a8);
    float b3 = vmax3(a9, aA, b0);
    float pm = vmax3(b1, b2, b3);

    if (!__all(pm - m_ <= 8.f)) {
      float om = fmaxf(pm, __shfl_xor(pm, 32, 64));
      float newm = fmaxf(m_, om);
      float alpha = vexp2(m_ - newm);
      m_ = newm;
      l_ *= alpha;
      #pragma unroll
      for (int r = 0; r < 16; ++r) {
        int qr = (r & 3) + 8 * (r >> 2) + 4 * hi;
        float ar = __shfl(alpha, qr, 32);
        acc0[r] *= ar;
        acc1[r] *= ar;
      }
    }

    #pragma unroll
    for (int r = 0; r < 16; ++r) s0[r] = vexp2(s0[r] - m_);
    #pragma unroll
    for (int r = 0; r < 16; ++r) s1[r] = vexp2(s1[r] - m_);

    {
      f32x16 ss = s0 + s1;
      float c0 = (ss[0] + ss[1]) + (ss[2] + ss[3]);
      float c1 = (ss[4] + ss[5]) + (ss[6] + ss[7]);
      float c2 = (ss[8] + ss[9]) + (ss[10] + ss[11]);
      float c3 = (ss[12] + ss[13]) + (ss[14] + ss[15]);
      l_ += (c0 + c1) + (c2 + c3);
    }

    __builtin_amdgcn_s_setprio(1);
    #pragma unroll
    for (int t = 0; t < 4; ++t) {
      const int base = (t & 1) * 8;
      uint32_t wA, wB, wC, wD;
      if (t < 2) {
        wA = cvt_pk_bf16(s0[base + 0], s0[base + 1]);
        wB = cvt_pk_bf16(s0[base + 2], s0[base + 3]);
        wC = cvt_pk_bf16(s0[base + 4], s0[base + 5]);
        wD = cvt_pk_bf16(s0[base + 6], s0[base + 7]);
      } else {
        wA = cvt_pk_bf16(s1[base + 0], s1[base + 1]);
        wB = cvt_pk_bf16(s1[base + 2], s1[base + 3]);
        wC = cvt_pk_bf16(s1[base + 4], s1[base + 5]);
        wD = cvt_pk_bf16(s1[base + 6], s1[base + 7]);
      }
      pl32_swap(wA, wC);
      pl32_swap(wB, wD);
      union { uint32_t u[4]; bf16x8 v8; } pu;
      pu.u[0] = wA; pu.u[1] = wB; pu.u[2] = wC; pu.u[3] = wD;
      bf16x8 v0 = ldsw(vbase, ql,      t * 32 + hi * 16);
      acc0 = __builtin_amdgcn_mfma_f32_32x32x16_bf16(pu.v8, v0, acc0, 0, 0, 0);
      bf16x8 v1 = ldsw(vbase, 32 + ql, t * 32 + hi * 16);
      acc1 = __builtin_amdgcn_mfma_f32_32x32x16_bf16(pu.v8, v1, acc1, 0, 0, 0);
    }
    __builtin_amdgcn_s_setprio(0);
  };

  auto QK = [&](int kc, f32x16& s0, f32x16& s1) {
    const u16* kbase = Ks[kc & 1];
    s0 = (f32x16){}; s1 = (f32x16){};
    __builtin_amdgcn_s_setprio(1);
    #pragma unroll
    for (int t = 0; t < 4; ++t) {
      bf16x8 k0 = ldsw(kbase, ql,      t * 32 + hi * 16);
      s0 = __builtin_amdgcn_mfma_f32_32x32x16_bf16(k0, qf[t], s0, 0, 0, 0);
      bf16x8 k1 = ldsw(kbase, 32 + ql, t * 32 + hi * 16);
      s1 = __builtin_amdgcn_mfma_f32_32x32x16_bf16(k1, qf[t], s1, 0, 0, 0);
    }
    __builtin_amdgcn_s_setprio(0);
  };

  auto TOP = [&](int kc) {
    if (kc < 15) {
      int nx = kc + 1;
      stage_swz<8192>(Kg + (nx << 12), Ks[nx & 1], tid);
      stage_vt(Vtb, Vs[nx % 3], nx, tid);
      asm volatile("s_waitcnt vmcnt(4)" ::: "memory");
    } else {
      asm volatile("s_waitcnt vmcnt(0)" ::: "memory");
    }
    __builtin_amdgcn_s_barrier();
    asm volatile("" ::: "memory");
  };
  auto BOT = [&]() {
    __builtin_amdgcn_s_barrier();
    asm volatile("" ::: "memory");
  };

  stage_swz<8192>(Kg, Ks[0], tid);
  stage_vt(Vtb, Vs[0], 0, tid);

  for (int kc2 = 0; kc2 < 16; kc2 += 2) {
    TOP(kc2);
    QK(kc2, pA0, pA1);
    if (kc2 > 0) SMPV(pB0, pB1, Vs[(kc2 + 2) % 3]);
    BOT();
    TOP(kc2 + 1);
    QK(kc2 + 1, pB0, pB1);
    SMPV(pA0, pA1, Vs[kc2 % 3]);
    BOT();
  }
  SMPV(pB0, pB1, Vs[0]);

  l_ += __shfl_xor(l_, 32, 64);
  float il = vrcp(l_);
  u16* ob = out + ((size_t)(b * SEQ + (qt << 7) + (wid << 5))) * CDIM + hh * 64 + ql;
  #pragma unroll
  for (int r = 0; r < 16; ++r) {
    int qr = (r & 3) + 8 * (r >> 2) + 4 * hi;
    float ilr = __shfl(il, qr, 32);
    ob[(size_t)qr * CDIM]      = f32_to_bf16(acc0[r] * ilr);
    ob[(size_t)qr * CDIM + 32] = f32_to_bf16(acc1[r] * ilr);
  }
}

extern "C" void kernel_launch(void* const* d_in, const int* in_sizes, int n_in,
                              void* d_out, int out_size, void* d_ws, size_t ws_size,
                              hipStream_t stream) {
  const float* x     = (const float*)d_in[0];
  const float* w_qkv = (const float*)d_in[1];
  const float* w_o   = (const float*)d_in[2];
  float* out = (float*)d_out;

  u16* xb    = (u16*)d_ws;
  u16* wqkvT = xb    + (size_t)MTOK * CDIM;
  u16* woT   = wqkvT + (size_t)NQKV * CDIM;
  u16* qb    = woT   + (size_t)CDIM * CDIM;
  u16* kb    = qb    + (size_t)NPAIR * SEQ * HD;
  u16* vb    = kb    + (size_t)NPAIR * SEQ * HD;   // stored transposed: [pair][d][n]
  u16* ao    = vb    + (size_t)NPAIR * SEQ * HD;

  prep_kernel<<<dim3(CVT_BLOCKS + TQKV_BLOCKS + 144), 256, 0, stream>>>(
      x, xb, w_qkv, wqkvT, w_o, woT);

  gemm_qkv8<<<dim3((MTOK / 128) * (NQKV / 128)), 512, 0, stream>>>(
      xb, wqkvT, qb, kb, vb);

  attn_kernel<<<dim3(NPAIR * 8), 256, 0, stream>>>(qb, kb, vb, ao);

  gemm_wo8<<<dim3((MTOK / 128) * (CDIM / 128)), 512, 0, stream>>>(
      ao, woT, out);
}

// Round 27
// 108.954 us; speedup vs baseline: 1.0592x; 1.0592x over previous
//
#include <hip/hip_runtime.h>
#include <hip/hip_bf16.h>
#include <stdint.h>
#include <math.h>

#define SEQ   1024
#define NHEAD 12
#define HD    64
#define CDIM  768
#define MTOK  8192
#define NQKV  2304
#define NPAIR 96   // BS*NHEAD

// q pre-scale: 1/sqrt(64) * log2(e)  (softmax done base-2)
#define QSCALE 0.18033688011112042f

typedef uint16_t u16;
typedef __attribute__((ext_vector_type(8)))  __bf16 bf16x8;
typedef __attribute__((ext_vector_type(4)))  float  f32x4;
typedef __attribute__((ext_vector_type(16))) float  f32x16;

__device__ __forceinline__ u16 f32_to_bf16(float f) {
  union { float f; uint32_t u; } cv; cv.f = f;
  uint32_t u = cv.u;
  return (u16)((u + 0x7FFFu + ((u >> 16) & 1u)) >> 16);
}

__device__ __forceinline__ uint32_t cvt_pk_bf16(float lo, float hi) {
  uint32_t r;
  asm("v_cvt_pk_bf16_f32 %0, %1, %2" : "=v"(r) : "v"(lo), "v"(hi));
  return r;
}

// v_permlane32_swap_b32: a.hi <-> b.lo
__device__ __forceinline__ void pl32_swap(uint32_t& a, uint32_t& b) {
  asm("v_permlane32_swap_b32 %0, %1" : "+v"(a), "+v"(b));
}

__device__ __forceinline__ float vexp2(float x) {
  float r; asm("v_exp_f32 %0, %1" : "=v"(r) : "v"(x)); return r;
}
__device__ __forceinline__ float vmax3(float a, float b, float c) {
  float d; asm("v_max3_f32 %0, %1, %2, %3" : "=v"(d) : "v"(a), "v"(b), "v"(c)); return d;
}
__device__ __forceinline__ float vrcp(float x) {
  float r; asm("v_rcp_f32 %0, %1" : "=v"(r) : "v"(x)); return r;
}

__device__ __forceinline__ void load_lds16(const u16* g, u16* l) {
  __builtin_amdgcn_global_load_lds(
      (const __attribute__((address_space(1))) uint32_t*)g,
      (__attribute__((address_space(3))) uint32_t*)l, 16, 0, 0);
}

// swizzled LDS read: 16B at (row, col-byte cb) of a 128B-row tile
__device__ __forceinline__ bf16x8 ldsw(const u16* base, int r, int cb) {
  int byte = (r << 7) + cb;
  byte ^= ((r & 7) << 4);
  return *(const bf16x8*)((const char*)base + byte);
}

// stage NB bytes (rows of 128B) from contiguous global, swizzled
template<int NB>
__device__ __forceinline__ void stage_swz(const u16* __restrict__ g, u16* l, int tid) {
  #pragma unroll
  for (int i = 0; i < NB / 4096; ++i) {
    int F = i * 4096 + tid * 16;
    int S = F ^ (((F >> 7) & 7) << 4);
    load_lds16(g + (S >> 1), l + (F >> 1));
  }
}

// stage V^T chunk: global vt[pair][d=64][n=1024], cols kc*64..+63 -> 64x128B tile
__device__ __forceinline__ void stage_vt(const u16* __restrict__ vtb, u16* l, int kc, int tid) {
  #pragma unroll
  for (int i = 0; i < 2; ++i) {
    int F = i * 4096 + tid * 16;
    int S = F ^ (((F >> 7) & 7) << 4);
    int r = S >> 7;
    int cb = S & 127;
    load_lds16(vtb + ((size_t)r << 10) + (kc << 6) + (cb >> 1), l + (F >> 1));
  }
}

// ---- fused prep: cvt_x (blocks 0..3071) | transpose w_qkv (3072..3503) |
// transpose w_o (3504..3647). ----
#define CVT_BLOCKS 3072                       // (MTOK*CDIM)/(256*8)
#define TQKV_BLOCKS 432                       // (CDIM/64)*(NQKV/64)
__global__ __launch_bounds__(256) void prep_kernel(const float* __restrict__ x,
                                                   u16* __restrict__ xb,
                                                   const float* __restrict__ wqkv,
                                                   u16* __restrict__ wqkvT,
                                                   const float* __restrict__ wo,
                                                   u16* __restrict__ woT) {
  __shared__ u16 t[64][66];
  int bid = blockIdx.x;
  int tid = threadIdx.x;

  if (bid < CVT_BLOCKS) {
    int i = bid * 256 + tid;
    const float4* p = (const float4*)x + (size_t)i * 2;
    float4 a = p[0], b = p[1];
    uint4 o;
    o.x = cvt_pk_bf16(a.x, a.y);
    o.y = cvt_pk_bf16(a.z, a.w);
    o.z = cvt_pk_bf16(b.x, b.y);
    o.w = cvt_pk_bf16(b.z, b.w);
    ((uint4*)xb)[i] = o;
    return;
  }

  const float* in;
  u16* outp;
  int N, bid2;
  if (bid < CVT_BLOCKS + TQKV_BLOCKS) {
    bid2 = bid - CVT_BLOCKS; in = wqkv; outp = wqkvT; N = NQKV;
  } else {
    bid2 = bid - CVT_BLOCKS - TQKV_BLOCKS; in = wo; outp = woT; N = CDIM;
  }
  const int K = CDIM, nbk = CDIM >> 6;        // 12
  int bk = bid2 % nbk, bn = bid2 / nbk;
  int k0 = bk << 6, n0 = bn << 6;
  #pragma unroll
  for (int i = 0; i < 16; ++i) {
    int idx = i * 256 + tid;
    int kr = idx >> 6, nc = idx & 63;
    t[kr][nc] = f32_to_bf16(in[(size_t)(k0 + kr) * N + n0 + nc]);
  }
  __syncthreads();
  #pragma unroll
  for (int i = 0; i < 16; ++i) {
    int idx = i * 256 + tid;
    int nr = idx >> 6, kc = idx & 63;
    outp[(size_t)(n0 + nr) * K + k0 + kc] = t[kc][nr];
  }
}

// ---- QKV GEMM (r24/r25 proven): 128x128 tile, BK=64, 8 waves (512 thr, 4Mx2N),
// dbuf + counted vmcnt(4), T2 swizzle, tn-major XCD order. ----
__global__ __launch_bounds__(512) void gemm_qkv8(const u16* __restrict__ A,
                                                 const u16* __restrict__ Bt,
                                                 u16* __restrict__ qb,
                                                 u16* __restrict__ kb,
                                                 u16* __restrict__ vb) {
  __shared__ u16 SH[4][8192];   // [0,1]=A dbuf (16KB each), [2,3]=B dbuf

  const int K = CDIM;
  int bid = blockIdx.x;
  int xcd = bid & 7, ii = bid >> 3;
  int tn = ii >> 3;
  int tm = (xcd << 3) + (ii & 7);
  int mBase = tm << 7, nBase = tn << 7;
  int tid = threadIdx.x;
  int lane = tid & 63, wid = tid >> 6;       // 0..7
  int wm = wid >> 1, wn = wid & 1;           // 4M x 2N
  int wr = wm << 5, wc = wn << 6;            // 32-row, 64-col wave tile
  int lr = lane & 15, lk = lane >> 4;

  const int nk = K >> 6;                     // 12

  auto STAGE = [&](int kt, int b) {
    #pragma unroll
    for (int i2 = 0; i2 < 2; ++i2) {
      int F = i2 * 8192 + tid * 16;          // byte in 16KB tile
      int row = F >> 7;
      int cb  = (F & 127) ^ ((row & 7) << 4);
      load_lds16(A + (size_t)(mBase + row) * K + kt * 64 + (cb >> 1), &SH[b][F >> 1]);
    }
    #pragma unroll
    for (int i2 = 0; i2 < 2; ++i2) {
      int F = i2 * 8192 + tid * 16;
      int row = F >> 7;
      int cb  = (F & 127) ^ ((row & 7) << 4);
      load_lds16(Bt + (size_t)(nBase + row) * K + kt * 64 + (cb >> 1), &SH[2 + b][F >> 1]);
    }
  };

  f32x4 acc[2][4] = {};

  STAGE(0, 0);
  for (int kt = 0; kt < nk; ++kt) {
    const int cur = kt & 1;
    if (kt + 1 < nk) {
      STAGE(kt + 1, cur ^ 1);
      asm volatile("s_waitcnt vmcnt(4)" ::: "memory");   // tile kt landed
    } else {
      asm volatile("s_waitcnt vmcnt(0)" ::: "memory");
    }
    __builtin_amdgcn_s_barrier();
    asm volatile("" ::: "memory");

    #pragma unroll
    for (int kk = 0; kk < 2; ++kk) {
      bf16x8 af[2], bfr[4];
      #pragma unroll
      for (int i2 = 0; i2 < 2; ++i2)
        af[i2]  = ldsw(SH[cur], wr + i2 * 16 + lr, kk * 64 + lk * 16);
      #pragma unroll
      for (int i2 = 0; i2 < 4; ++i2)
        bfr[i2] = ldsw(SH[2 + cur], wc + i2 * 16 + lr, kk * 64 + lk * 16);
      #pragma unroll
      for (int mi = 0; mi < 2; ++mi)
        #pragma unroll
        for (int ni = 0; ni < 4; ++ni)
          acc[mi][ni] = __builtin_amdgcn_mfma_f32_16x16x32_bf16(af[mi], bfr[ni], acc[mi][ni], 0, 0, 0);
    }

    __builtin_amdgcn_s_barrier();
    asm volatile("" ::: "memory");
  }
  // trailing barrier above: all reads done; SH free for epilogue

  int c0 = nBase + wc;                 // 64-aligned; wave spans one head
  int s  = c0 / CDIM;
  int rem0 = c0 - s * CDIM, hh = rem0 >> 6;
  u16* ereg = &SH[0][0] + wid * 2048;  // 4KB per wave (8 waves = 32KB)

  if (s != 2) {
    // region 32 rows x 64 cols, 128B rows, XOR-swizzled
    #pragma unroll
    for (int mi = 0; mi < 2; ++mi)
      #pragma unroll
      for (int ni = 0; ni < 4; ++ni)
        #pragma unroll
        for (int j = 0; j < 4; ++j) {
          float val = acc[mi][ni][j];
          if (s == 0) val *= QSCALE;
          int r = mi * 16 + lk * 4 + j;      // 0..31
          int c = ni * 16 + lr;              // 0..63
          int byte = (r << 7) + (((c << 1)) ^ ((r & 7) << 4));
          *(u16*)((char*)ereg + byte) = f32_to_bf16(val);
        }
    int row = lane & 31, hf = lane >> 5;
    int mrow = mBase + wr + row;
    int bb = mrow >> 10, nn = mrow & 1023;
    u16* buf = (s == 0) ? qb : kb;
    u16* dst = buf + (((size_t)(bb * NHEAD + hh)) << 16) + nn * 64 + hf * 32;
    #pragma unroll
    for (int rc2 = 0; rc2 < 4; ++rc2) {
      int rc = (rc2 + (row >> 3)) & 3;
      int cbyte = hf * 64 + rc * 16;
      int byte = (row << 7) + (cbyte ^ ((row & 7) << 4));
      bf16x8 vv = *(const bf16x8*)((const char*)ereg + byte);
      *(bf16x8*)(dst + rc * 8) = vv;
    }
  } else {
    // vT slice: transpose to region 64 d-rows x 32 n-cols, 64B rows
    #pragma unroll
    for (int mi = 0; mi < 2; ++mi)
      #pragma unroll
      for (int ni = 0; ni < 4; ++ni)
        #pragma unroll
        for (int j = 0; j < 4; ++j) {
          int n_ = mi * 16 + lk * 4 + j;     // 0..31 (m-local)
          int d_ = ni * 16 + lr;             // 0..63
          int byte = (d_ << 6) + (((n_ << 1)) ^ (((d_ >> 1) & 3) << 4));
          *(u16*)((char*)ereg + byte) = f32_to_bf16(acc[mi][ni][j]);
        }
    int m0 = mBase + wr;
    int bb = m0 >> 10, nn0 = m0 & 1023;
    u16* dst = vb + (((size_t)(bb * NHEAD + hh)) << 16) + ((size_t)lane << 10) + nn0;
    #pragma unroll
    for (int rc2 = 0; rc2 < 4; ++rc2) {
      int rc = (rc2 + (lane >> 4)) & 3;
      int byte = (lane << 6) + ((rc * 16) ^ (((lane >> 1) & 3) << 4));
      bf16x8 vv = *(const bf16x8*)((const char*)ereg + byte);
      *(bf16x8*)(dst + rc * 8) = vv;
    }
  }
}

// ---- w_o GEMM (r25 proven): 8 waves, BK=64, dbuf + vmcnt(4), f32 repack ----
__global__ __launch_bounds__(512) void gemm_wo8(const u16* __restrict__ A,
                                                const u16* __restrict__ Bt,
                                                float* __restrict__ Cf) {
  __shared__ u16 SH[4][8192];

  const int K = CDIM, N = CDIM;
  int bid = blockIdx.x;
  int xcd = bid & 7, ii = bid >> 3;
  int tn = ii >> 3;
  int tm = (xcd << 3) + (ii & 7);
  int mBase = tm << 7, nBase = tn << 7;
  int tid = threadIdx.x;
  int lane = tid & 63, wid = tid >> 6;
  int wm = wid >> 1, wn = wid & 1;
  int wr = wm << 5, wc = wn << 6;
  int lr = lane & 15, lk = lane >> 4;

  const int nk = K >> 6;

  auto STAGE = [&](int kt, int b) {
    #pragma unroll
    for (int i2 = 0; i2 < 2; ++i2) {
      int F = i2 * 8192 + tid * 16;
      int row = F >> 7;
      int cb  = (F & 127) ^ ((row & 7) << 4);
      load_lds16(A + (size_t)(mBase + row) * K + kt * 64 + (cb >> 1), &SH[b][F >> 1]);
    }
    #pragma unroll
    for (int i2 = 0; i2 < 2; ++i2) {
      int F = i2 * 8192 + tid * 16;
      int row = F >> 7;
      int cb  = (F & 127) ^ ((row & 7) << 4);
      load_lds16(Bt + (size_t)(nBase + row) * K + kt * 64 + (cb >> 1), &SH[2 + b][F >> 1]);
    }
  };

  f32x4 acc[2][4] = {};

  STAGE(0, 0);
  for (int kt = 0; kt < nk; ++kt) {
    const int cur = kt & 1;
    if (kt + 1 < nk) {
      STAGE(kt + 1, cur ^ 1);
      asm volatile("s_waitcnt vmcnt(4)" ::: "memory");
    } else {
      asm volatile("s_waitcnt vmcnt(0)" ::: "memory");
    }
    __builtin_amdgcn_s_barrier();
    asm volatile("" ::: "memory");

    #pragma unroll
    for (int kk = 0; kk < 2; ++kk) {
      bf16x8 af[2], bfr[4];
      #pragma unroll
      for (int i2 = 0; i2 < 2; ++i2)
        af[i2]  = ldsw(SH[cur], wr + i2 * 16 + lr, kk * 64 + lk * 16);
      #pragma unroll
      for (int i2 = 0; i2 < 4; ++i2)
        bfr[i2] = ldsw(SH[2 + cur], wc + i2 * 16 + lr, kk * 64 + lk * 16);
      #pragma unroll
      for (int mi = 0; mi < 2; ++mi)
        #pragma unroll
        for (int ni = 0; ni < 4; ++ni)
          acc[mi][ni] = __builtin_amdgcn_mfma_f32_16x16x32_bf16(af[mi], bfr[ni], acc[mi][ni], 0, 0, 0);
    }

    __builtin_amdgcn_s_barrier();
    asm volatile("" ::: "memory");
  }

  // f32 repack: 32 rows x 256B, XOR-swizzled; 8KB/wave
  char* ereg = (char*)(&SH[0][0]) + wid * 8192;
  #pragma unroll
  for (int mi = 0; mi < 2; ++mi)
    #pragma unroll
    for (int ni = 0; ni < 4; ++ni)
      #pragma unroll
      for (int j = 0; j < 4; ++j) {
        int r = mi * 16 + lk * 4 + j;        // 0..31
        int byte = (r << 8) + (((ni * 16 + lr) << 2) ^ ((r & 7) << 4));
        *(float*)(ereg + byte) = acc[mi][ni][j];
      }
  int row = lane & 31, hf = lane >> 5;
  float* dst = Cf + (size_t)(mBase + wr + row) * N + (nBase + wc) + hf * 32;
  #pragma unroll
  for (int rc2 = 0; rc2 < 8; ++rc2) {
    int rc = (rc2 + (row >> 2)) & 7;
    int cbyte = hf * 128 + rc * 16;
    int byte = (row << 8) + (cbyte ^ ((row & 7) << 4));
    f32x4 vv = *(const f32x4*)(ereg + byte);
    *(f32x4*)(dst + rc * 4) = vv;
  }
}

// ---- flash attention v9 (r18 best): T15 pipeline, in-lane l ----
__global__ __launch_bounds__(256, 3) void attn_kernel(const u16* __restrict__ q,
                                                      const u16* __restrict__ k,
                                                      const u16* __restrict__ v,
                                                      u16* __restrict__ out) {
  __shared__ u16 Ks[2][4096];
  __shared__ u16 Vs[3][4096];   // V^T slots: chunk c -> slot c%3

  int bid = blockIdx.x;
  int wgid = (bid & 7) * 96 + (bid >> 3);   // 768 blocks, pairs XCD-local
  int pair = wgid >> 3;
  int qt   = wgid & 7;
  int b = pair / NHEAD, hh = pair - b * NHEAD;
  const u16* Kg  = k + ((size_t)pair << 16);
  const u16* Vtb = v + ((size_t)pair << 16);
  int tid = threadIdx.x, lane = tid & 63, wid = tid >> 6;
  int ql = lane & 31, hi = lane >> 5;

  const u16* Qrow = q + ((size_t)pair << 16) + (size_t)((qt << 7) + (wid << 5) + ql) * 64;
  bf16x8 qf[4];
  #pragma unroll
  for (int t = 0; t < 4; ++t)
    qf[t] = *(const bf16x8*)(Qrow + t * 16 + hi * 8);

  float m_ = -1e30f, l_ = 0.f;  // per-lane: q = ql, k-half = hi (l_ partial)
  f32x16 acc0 = {}, acc1 = {};
  f32x16 pA0, pA1, pB0, pB1;    // S-state: even chunks in pA, odd in pB

  auto SMPV = [&](f32x16& s0, f32x16& s1, const u16* vbase) {
    float a0 = vmax3(s0[0],  s0[1],  s0[2]);
    float a1 = vmax3(s0[3],  s0[4],  s0[5]);
    float a2 = vmax3(s0[6],  s0[7],  s0[8]);
    float a3 = vmax3(s0[9],  s0[10], s0[11]);
    float a4 = vmax3(s0[12], s0[13], s0[14]);
    float a5 = vmax3(s0[15], s1[0],  s1[1]);
    float a6 = vmax3(s1[2],  s1[3],  s1[4]);
    float a7 = vmax3(s1[5],  s1[6],  s1[7]);
    float a8 = vmax3(s1[8],  s1[9],  s1[10]);
    float a9 = vmax3(s1[11], s1[12], s1[13]);
    float aA = fmaxf(s1[14], s1[15]);
    float b0 = vmax3(a0, a1, a2);
    float b1 = vmax3(a3, a4, a5);
    float b2 = vmax3(a6, a7, a8);
    float b3 = vmax3(a9, aA, b0);
    float pm = vmax3(b1, b2, b3);

    if (!__all(pm - m_ <= 8.f)) {
      float om = fmaxf(pm, __shfl_xor(pm, 32, 64));
      float newm = fmaxf(m_, om);
      float alpha = vexp2(m_ - newm);
      m_ = newm;
      l_ *= alpha;
      #pragma unroll
      for (int r = 0; r < 16; ++r) {
        int qr = (r & 3) + 8 * (r >> 2) + 4 * hi;
        float ar = __shfl(alpha, qr, 32);
        acc0[r] *= ar;
        acc1[r] *= ar;
      }
    }

    #pragma unroll
    for (int r = 0; r < 16; ++r) s0[r] = vexp2(s0[r] - m_);
    #pragma unroll
    for (int r = 0; r < 16; ++r) s1[r] = vexp2(s1[r] - m_);

    {
      f32x16 ss = s0 + s1;
      float c0 = (ss[0] + ss[1]) + (ss[2] + ss[3]);
      float c1 = (ss[4] + ss[5]) + (ss[6] + ss[7]);
      float c2 = (ss[8] + ss[9]) + (ss[10] + ss[11]);
      float c3 = (ss[12] + ss[13]) + (ss[14] + ss[15]);
      l_ += (c0 + c1) + (c2 + c3);
    }

    __builtin_amdgcn_s_setprio(1);
    #pragma unroll
    for (int t = 0; t < 4; ++t) {
      const int base = (t & 1) * 8;
      uint32_t wA, wB, wC, wD;
      if (t < 2) {
        wA = cvt_pk_bf16(s0[base + 0], s0[base + 1]);
        wB = cvt_pk_bf16(s0[base + 2], s0[base + 3]);
        wC = cvt_pk_bf16(s0[base + 4], s0[base + 5]);
        wD = cvt_pk_bf16(s0[base + 6], s0[base + 7]);
      } else {
        wA = cvt_pk_bf16(s1[base + 0], s1[base + 1]);
        wB = cvt_pk_bf16(s1[base + 2], s1[base + 3]);
        wC = cvt_pk_bf16(s1[base + 4], s1[base + 5]);
        wD = cvt_pk_bf16(s1[base + 6], s1[base + 7]);
      }
      pl32_swap(wA, wC);
      pl32_swap(wB, wD);
      union { uint32_t u[4]; bf16x8 v8; } pu;
      pu.u[0] = wA; pu.u[1] = wB; pu.u[2] = wC; pu.u[3] = wD;
      bf16x8 v0 = ldsw(vbase, ql,      t * 32 + hi * 16);
      acc0 = __builtin_amdgcn_mfma_f32_32x32x16_bf16(pu.v8, v0, acc0, 0, 0, 0);
      bf16x8 v1 = ldsw(vbase, 32 + ql, t * 32 + hi * 16);
      acc1 = __builtin_amdgcn_mfma_f32_32x32x16_bf16(pu.v8, v1, acc1, 0, 0, 0);
    }
    __builtin_amdgcn_s_setprio(0);
  };

  auto QK = [&](int kc, f32x16& s0, f32x16& s1) {
    const u16* kbase = Ks[kc & 1];
    s0 = (f32x16){}; s1 = (f32x16){};
    __builtin_amdgcn_s_setprio(1);
    #pragma unroll
    for (int t = 0; t < 4; ++t) {
      bf16x8 k0 = ldsw(kbase, ql,      t * 32 + hi * 16);
      s0 = __builtin_amdgcn_mfma_f32_32x32x16_bf16(k0, qf[t], s0, 0, 0, 0);
      bf16x8 k1 = ldsw(kbase, 32 + ql, t * 32 + hi * 16);
      s1 = __builtin_amdgcn_mfma_f32_32x32x16_bf16(k1, qf[t], s1, 0, 0, 0);
    }
    __builtin_amdgcn_s_setprio(0);
  };

  auto TOP = [&](int kc) {
    if (kc < 15) {
      int nx = kc + 1;
      stage_swz<8192>(Kg + (nx << 12), Ks[nx & 1], tid);
      stage_vt(Vtb, Vs[nx % 3], nx, tid);
      asm volatile("s_waitcnt vmcnt(4)" ::: "memory");
    } else {
      asm volatile("s_waitcnt vmcnt(0)" ::: "memory");
    }
    __builtin_amdgcn_s_barrier();
    asm volatile("" ::: "memory");
  };
  auto BOT = [&]() {
    __builtin_amdgcn_s_barrier();
    asm volatile("" ::: "memory");
  };

  stage_swz<8192>(Kg, Ks[0], tid);
  stage_vt(Vtb, Vs[0], 0, tid);

  for (int kc2 = 0; kc2 < 16; kc2 += 2) {
    TOP(kc2);
    QK(kc2, pA0, pA1);
    if (kc2 > 0) SMPV(pB0, pB1, Vs[(kc2 + 2) % 3]);
    BOT();
    TOP(kc2 + 1);
    QK(kc2 + 1, pB0, pB1);
    SMPV(pA0, pA1, Vs[kc2 % 3]);
    BOT();
  }
  SMPV(pB0, pB1, Vs[0]);

  l_ += __shfl_xor(l_, 32, 64);
  float il = vrcp(l_);
  u16* ob = out + ((size_t)(b * SEQ + (qt << 7) + (wid << 5))) * CDIM + hh * 64 + ql;
  #pragma unroll
  for (int r = 0; r < 16; ++r) {
    int qr = (r & 3) + 8 * (r >> 2) + 4 * hi;
    float ilr = __shfl(il, qr, 32);
    ob[(size_t)qr * CDIM]      = f32_to_bf16(acc0[r] * ilr);
    ob[(size_t)qr * CDIM + 32] = f32_to_bf16(acc1[r] * ilr);
  }
}

extern "C" void kernel_launch(void* const* d_in, const int* in_sizes, int n_in,
                              void* d_out, int out_size, void* d_ws, size_t ws_size,
                              hipStream_t stream) {
  const float* x     = (const float*)d_in[0];
  const float* w_qkv = (const float*)d_in[1];
  const float* w_o   = (const float*)d_in[2];
  float* out = (float*)d_out;

  u16* xb    = (u16*)d_ws;
  u16* wqkvT = xb    + (size_t)MTOK * CDIM;
  u16* woT   = wqkvT + (size_t)NQKV * CDIM;
  u16* qb    = woT   + (size_t)CDIM * CDIM;
  u16* kb    = qb    + (size_t)NPAIR * SEQ * HD;
  u16* vb    = kb    + (size_t)NPAIR * SEQ * HD;   // stored transposed: [pair][d][n]
  u16* ao    = vb    + (size_t)NPAIR * SEQ * HD;

  prep_kernel<<<dim3(CVT_BLOCKS + TQKV_BLOCKS + 144), 256, 0, stream>>>(
      x, xb, w_qkv, wqkvT, w_o, woT);

  gemm_qkv8<<<dim3((MTOK / 128) * (NQKV / 128)), 512, 0, stream>>>(
      xb, wqkvT, qb, kb, vb);

  attn_kernel<<<dim3(NPAIR * 8), 256, 0, stream>>>(qb, kb, vb, ao);

  gemm_wo8<<<dim3((MTOK / 128) * (CDIM / 128)), 512, 0, stream>>>(
      ao, woT, out);
}